// Round 7
// baseline (76.811 us; speedup 1.0000x reference)
//
#include <hip/hip_runtime.h>
#include <cstddef>

constexpr int CB  = 2;
constexpr int CH  = 16;
constexpr int CS  = 4096;
constexpr int CD  = 64;
constexpr int CG  = 64;
constexpr int CBH = CB * CH;
constexpr int NW1   = CS / 128;   // part-1 windows per bh (32)
constexpr int G2NCH = 64;         // part-2 64-key windows per bh
constexpr int NPART = G2NCH;      // partials per (bh,q) -- same granularity as r6

typedef float  f32x16 __attribute__((ext_vector_type(16)));
typedef short  short8 __attribute__((ext_vector_type(8)));
typedef float  fvec4  __attribute__((ext_vector_type(4)));

union U8 { unsigned u[4]; short8 s; };

__device__ __forceinline__ unsigned short f2bf(float x) {
  unsigned u = __float_as_uint(x);
  unsigned r = u + 0x7fffu + ((u >> 16) & 1u);  // RNE
  return (unsigned short)(r >> 16);
}
__device__ __forceinline__ unsigned pk2(float lo, float hi) {
  return (unsigned)f2bf(lo) | ((unsigned)f2bf(hi) << 16);
}
__device__ __forceinline__ f32x16 zero16() {
  f32x16 z;
#pragma unroll
  for (int i = 0; i < 16; ++i) z[i] = 0.f;
  return z;
}

// P -> MFMA-A fragment relayout for one 16-key slot (exchange across lane^32).
#define MK_PA(dst, hi_, a0,a1,a2,a3,a4,a5,a6,a7)                         \
  {                                                                      \
    unsigned x0 = pk2(a0, a1), x1 = pk2(a2, a3);                         \
    unsigned y0 = pk2(a4, a5), y1 = pk2(a6, a7);                         \
    unsigned t0 = (unsigned)__shfl_xor((int)((hi_) ? x0 : y0), 32);      \
    if (hi_) x0 = t0; else y0 = t0;                                      \
    unsigned t1 = (unsigned)__shfl_xor((int)((hi_) ? x1 : y1), 32);      \
    if (hi_) x1 = t1; else y1 = t1;                                      \
    U8 w_; w_.u[0] = x0; w_.u[1] = x1; w_.u[2] = y0; w_.u[3] = y1;       \
    dst = w_.s;                                                          \
  }

// ---------------------------------------------------------------------------
__global__ void k_setup(const int* __restrict__ mask,
                        int* __restrict__ gpos, int* __restrict__ gcount) {
  const int b = blockIdx.x;
  const int t = threadIdx.x;  // 64
  __shared__ int cnt[64];
  if (t < CG) gpos[b * CG + t] = 0;
  const int span = CS / 64;
  const int base = b * CS + t * span;
  int c = 0;
  for (int i = 0; i < span; ++i) c += (mask[base + i] > 0) ? 1 : 0;
  cnt[t] = c;
  __syncthreads();
  int pre = 0;
  for (int j = 0; j < t; ++j) pre += cnt[j];
  for (int i = 0; i < span; ++i) {
    if (mask[base + i] > 0) {
      if (pre < CG) gpos[b * CG + pre] = t * span + i;
      ++pre;
    }
  }
  if (t == 63) gcount[b] = (pre < CG) ? pre : CG;
}

// ---------------------------------------------------------------------------
// Fused main kernel, 16 KB LDS both roles -> 8 blocks/CU.
// blockIdx.x < NW1 : part-1 (128 q-rows x 64 global KVs).
// else             : part-2 (64 global q x one 64-key window); waves split
//                    as (q-tile, d-half); QK^T/softmax duplicated per d-half.
// ---------------------------------------------------------------------------
struct __align__(16) SMem {
  short sK[64 * 64];   // [key][d] bf16, 128B rows, XOR-swizzled
  short sVT[64 * 64];  // [d][key] bf16, 128B rows, XOR-swizzled
};

__global__ __launch_bounds__(256, 8) void k_main(
    const float* __restrict__ q, const float* __restrict__ k,
    const float* __restrict__ v,
    const int* __restrict__ gpos, const int* __restrict__ gcount,
    float* __restrict__ ctx, float* __restrict__ probs,
    float* __restrict__ pm, float* __restrict__ pl,
    unsigned short* __restrict__ pctx) {
  __shared__ SMem sm;
  __shared__ int gp[CG];
  __shared__ int gc_s;
  const int bh = blockIdx.y, b = bh / CH, t = threadIdx.x;
  if (t < CG) gp[t] = gpos[b * CG + t];
  if (t == 0) gc_s = gcount[b];
  __syncthreads();

  const int lane = t & 63, wv = t >> 6;
  const int hi = lane >> 5, ql = lane & 31;
  const unsigned kswz = (unsigned)((ql & 7) << 4);

  if (blockIdx.x < NW1) {
    // ------------------------------ part 1 ------------------------------
    if (t < 128) {  // stage gathered K rows -> sK[key][d]
      const int row = t >> 1, c0 = (t & 1) * 32;
      const float* src = k + ((size_t)(bh * CS + gp[row])) * CD + c0;
      const unsigned swz = (unsigned)((row & 7) << 4);
      char* rb = (char*)sm.sK + row * 128;
#pragma unroll
      for (int i = 0; i < 4; ++i) {
        fvec4 a = *(const fvec4*)(src + i * 8);
        fvec4 c = *(const fvec4*)(src + i * 8 + 4);
        U8 w;
        w.u[0] = pk2(a[0], a[1]); w.u[1] = pk2(a[2], a[3]);
        w.u[2] = pk2(c[0], c[1]); w.u[3] = pk2(c[2], c[3]);
        *(short8*)(rb + (((unsigned)(c0 * 2 + i * 16)) ^ swz)) = w.s;
      }
    } else {  // stage gathered V transposed -> sVT[d][key]
      const int u = t - 128;
      const int kg = u >> 4, cg = u & 15;
      fvec4 rv[8];
#pragma unroll
      for (int i = 0; i < 8; ++i)
        rv[i] = *(const fvec4*)(v + ((size_t)(bh * CS + gp[8 * kg + i])) * CD + 4 * cg);
#pragma unroll
      for (int c = 0; c < 4; ++c) {
        const int row = 4 * cg + c;
        U8 w;
        w.u[0] = pk2(rv[0][c], rv[1][c]); w.u[1] = pk2(rv[2][c], rv[3][c]);
        w.u[2] = pk2(rv[4][c], rv[5][c]); w.u[3] = pk2(rv[6][c], rv[7][c]);
        *(short8*)((char*)sm.sVT + row * 128 +
                   (((unsigned)(16 * kg)) ^ ((unsigned)((row & 7) << 4)))) = w.s;
      }
    }
    __syncthreads();

    const int qrow = blockIdx.x * 128 + wv * 32 + ql;
    const float* qr = q + ((size_t)(bh * CS + qrow)) * CD + hi * 8;
    short8 qf[4];
#pragma unroll
    for (int s = 0; s < 4; ++s) {
      fvec4 a = *(const fvec4*)(qr + s * 16);
      fvec4 c = *(const fvec4*)(qr + s * 16 + 4);
      U8 w;
      w.u[0] = pk2(a[0] * 0.125f, a[1] * 0.125f);
      w.u[1] = pk2(a[2] * 0.125f, a[3] * 0.125f);
      w.u[2] = pk2(c[0] * 0.125f, c[1] * 0.125f);
      w.u[3] = pk2(c[2] * 0.125f, c[3] * 0.125f);
      qf[s] = w.s;
    }

    f32x16 acc0 = zero16(), acc1 = zero16();
#pragma unroll
    for (int s = 0; s < 4; ++s) {
      const unsigned off = ((unsigned)(32 * s + 16 * hi)) ^ kswz;
      short8 k0 = *(const short8*)((char*)sm.sK + ql * 128 + off);
      acc0 = __builtin_amdgcn_mfma_f32_32x32x16_bf16(k0, qf[s], acc0, 0, 0, 0);
      short8 k1 = *(const short8*)((char*)sm.sK + (32 + ql) * 128 + off);
      acc1 = __builtin_amdgcn_mfma_f32_32x32x16_bf16(k1, qf[s], acc1, 0, 0, 0);
    }

    const int gc = gc_s;
    float p0[16], p1[16];
    float m = -1e30f;
#pragma unroll
    for (int r = 0; r < 16; ++r) {
      const int key0 = (r & 3) + 8 * (r >> 2) + 4 * hi;
      float x0 = (key0 < gc) ? acc0[r] : -1e30f;
      float x1 = (key0 + 32 < gc) ? acc1[r] : -1e30f;
      p0[r] = x0; p1[r] = x1;
      m = fmaxf(m, fmaxf(x0, x1));
    }
    m = fmaxf(m, __shfl_xor(m, 32));
    float ls = 0.f;
#pragma unroll
    for (int r = 0; r < 16; ++r) {
      p0[r] = __expf(p0[r] - m); ls += p0[r];
      p1[r] = __expf(p1[r] - m); ls += p1[r];
    }
    ls += __shfl_xor(ls, 32);
    const float inv = 1.0f / ls;
#pragma unroll
    for (int r = 0; r < 16; ++r) { p0[r] *= inv; p1[r] *= inv; }

    float* prow = probs + ((size_t)(bh * CS + qrow)) * CG;
#pragma unroll
    for (int g4 = 0; g4 < 4; ++g4) {
      fvec4 o0 = {p0[4 * g4], p0[4 * g4 + 1], p0[4 * g4 + 2], p0[4 * g4 + 3]};
      fvec4 o1 = {p1[4 * g4], p1[4 * g4 + 1], p1[4 * g4 + 2], p1[4 * g4 + 3]};
      *(fvec4*)(prow + 8 * g4 + 4 * hi) = o0;
      *(fvec4*)(prow + 8 * g4 + 4 * hi + 32) = o1;
    }

    short8 pa0, pa1, pa2, pa3;
    MK_PA(pa0, hi, p0[0], p0[1], p0[2], p0[3], p0[4], p0[5], p0[6], p0[7]);
    MK_PA(pa1, hi, p0[8], p0[9], p0[10], p0[11], p0[12], p0[13], p0[14], p0[15]);
    MK_PA(pa2, hi, p1[0], p1[1], p1[2], p1[3], p1[4], p1[5], p1[6], p1[7]);
    MK_PA(pa3, hi, p1[8], p1[9], p1[10], p1[11], p1[12], p1[13], p1[14], p1[15]);

    f32x16 oc0 = zero16(), oc1 = zero16();
#pragma unroll
    for (int s = 0; s < 4; ++s) {
      const short8 pas = (s == 0) ? pa0 : (s == 1) ? pa1 : (s == 2) ? pa2 : pa3;
      const unsigned off = ((unsigned)(32 * s + 16 * hi)) ^ kswz;
      short8 v0 = *(const short8*)((char*)sm.sVT + ql * 128 + off);
      oc0 = __builtin_amdgcn_mfma_f32_32x32x16_bf16(pas, v0, oc0, 0, 0, 0);
      short8 v1 = *(const short8*)((char*)sm.sVT + (32 + ql) * 128 + off);
      oc1 = __builtin_amdgcn_mfma_f32_32x32x16_bf16(pas, v1, oc1, 0, 0, 0);
    }

    float* cb = ctx + ((size_t)(bh * CS + blockIdx.x * 128 + wv * 32)) * CD;
#pragma unroll
    for (int r = 0; r < 16; ++r) {
      const int qr2 = (r & 3) + 8 * (r >> 2) + 4 * hi;
      cb[(size_t)qr2 * CD + ql] = oc0[r];
      cb[(size_t)qr2 * CD + 32 + ql] = oc1[r];
    }
  } else {
    // ------------------------------ part 2 ------------------------------
    const int bx = blockIdx.x - NW1;
    const int kwin = bx * 64;
    if (t < 128) {  // stage K rows -> sK[key][d]
      const int row = t >> 1, c0 = (t & 1) * 32;
      const float* src = k + ((size_t)(bh * CS + kwin + row)) * CD + c0;
      const unsigned swz = (unsigned)((row & 7) << 4);
      char* rb = (char*)sm.sK + row * 128;
#pragma unroll
      for (int i = 0; i < 4; ++i) {
        fvec4 a = *(const fvec4*)(src + i * 8);
        fvec4 c = *(const fvec4*)(src + i * 8 + 4);
        U8 w;
        w.u[0] = pk2(a[0], a[1]); w.u[1] = pk2(a[2], a[3]);
        w.u[2] = pk2(c[0], c[1]); w.u[3] = pk2(c[2], c[3]);
        *(short8*)(rb + (((unsigned)(c0 * 2 + i * 16)) ^ swz)) = w.s;
      }
    } else {  // stage V transposed -> sVT[d][key]
      const int u = t - 128;
      const int kg = u >> 4, cg = u & 15;
      fvec4 rv[8];
#pragma unroll
      for (int i = 0; i < 8; ++i)
        rv[i] = *(const fvec4*)(
            v + ((size_t)(bh * CS + kwin + 8 * kg + i)) * CD + 4 * cg);
#pragma unroll
      for (int c = 0; c < 4; ++c) {
        const int row = 4 * cg + c;
        U8 w;
        w.u[0] = pk2(rv[0][c], rv[1][c]); w.u[1] = pk2(rv[2][c], rv[3][c]);
        w.u[2] = pk2(rv[4][c], rv[5][c]); w.u[3] = pk2(rv[6][c], rv[7][c]);
        *(short8*)((char*)sm.sVT + row * 128 +
                   (((unsigned)(16 * kg)) ^ ((unsigned)((row & 7) << 4)))) = w.s;
      }
    }
    __syncthreads();

    const int qt = wv & 1, dh = wv >> 1;   // q-tile, output-d half
    const int qslot = qt * 32 + ql;

    const float* qr = q + ((size_t)(bh * CS + gp[qslot])) * CD + hi * 8;
    short8 qf[4];
#pragma unroll
    for (int s = 0; s < 4; ++s) {
      fvec4 a = *(const fvec4*)(qr + s * 16);
      fvec4 c = *(const fvec4*)(qr + s * 16 + 4);
      U8 w;
      w.u[0] = pk2(a[0] * 0.125f, a[1] * 0.125f);
      w.u[1] = pk2(a[2] * 0.125f, a[3] * 0.125f);
      w.u[2] = pk2(c[0] * 0.125f, c[1] * 0.125f);
      w.u[3] = pk2(c[2] * 0.125f, c[3] * 0.125f);
      qf[s] = w.s;
    }

    // QK^T over the 64-key window (duplicated across the d-half wave pair)
    f32x16 acc0 = zero16(), acc1 = zero16();
#pragma unroll
    for (int s = 0; s < 4; ++s) {
      const unsigned off = ((unsigned)(32 * s + 16 * hi)) ^ kswz;
      short8 k0 = *(const short8*)((char*)sm.sK + ql * 128 + off);
      acc0 = __builtin_amdgcn_mfma_f32_32x32x16_bf16(k0, qf[s], acc0, 0, 0, 0);
      short8 k1 = *(const short8*)((char*)sm.sK + (32 + ql) * 128 + off);
      acc1 = __builtin_amdgcn_mfma_f32_32x32x16_bf16(k1, qf[s], acc1, 0, 0, 0);
    }

    float p0[16], p1[16];
    float m = -1e30f;
#pragma unroll
    for (int r = 0; r < 16; ++r) {
      p0[r] = acc0[r]; p1[r] = acc1[r];
      m = fmaxf(m, fmaxf(p0[r], p1[r]));
    }
    m = fmaxf(m, __shfl_xor(m, 32));
    float ls = 0.f;
#pragma unroll
    for (int r = 0; r < 16; ++r) {
      p0[r] = __expf(p0[r] - m); ls += p0[r];
      p1[r] = __expf(p1[r] - m); ls += p1[r];
    }
    ls += __shfl_xor(ls, 32);

    short8 pa0, pa1, pa2, pa3;
    MK_PA(pa0, hi, p0[0], p0[1], p0[2], p0[3], p0[4], p0[5], p0[6], p0[7]);
    MK_PA(pa1, hi, p0[8], p0[9], p0[10], p0[11], p0[12], p0[13], p0[14], p0[15]);
    MK_PA(pa2, hi, p1[0], p1[1], p1[2], p1[3], p1[4], p1[5], p1[6], p1[7]);
    MK_PA(pa3, hi, p1[8], p1[9], p1[10], p1[11], p1[12], p1[13], p1[14], p1[15]);

    // PV: only this wave's 32 output-d columns (rows dh*32+ql of sVT)
    f32x16 oc = zero16();
#pragma unroll
    for (int s = 0; s < 4; ++s) {
      const short8 pas = (s == 0) ? pa0 : (s == 1) ? pa1 : (s == 2) ? pa2 : pa3;
      const unsigned off = ((unsigned)(32 * s + 16 * hi)) ^ kswz;
      short8 vv = *(const short8*)((char*)sm.sVT + (dh * 32 + ql) * 128 + off);
      oc = __builtin_amdgcn_mfma_f32_32x32x16_bf16(pas, vv, oc, 0, 0, 0);
    }

    if (dh == 0 && hi == 0) {
      const size_t o = ((size_t)(bh * NPART + bx)) * CG + qslot;
      pm[o] = m;
      pl[o] = ls;
    }
    unsigned short* po =
        pctx + (((size_t)(bh * NPART + bx)) * CG + qt * 32) * CD;
#pragma unroll
    for (int r = 0; r < 16; ++r) {
      const int qr2 = (r & 3) + 8 * (r >> 2) + 4 * hi;
      po[(size_t)qr2 * CD + dh * 32 + ql] = f2bf(oc[r]);
    }
  }
}

// ---------------------------------------------------------------------------
__global__ __launch_bounds__(64) void k_combine(
    const float* __restrict__ pm, const float* __restrict__ pl,
    const unsigned short* __restrict__ pctx,
    const int* __restrict__ gpos, const int* __restrict__ gcount,
    float* __restrict__ ctx) {
  const int g = blockIdx.x;
  const int bh = blockIdx.y;
  const int b = bh / CH;
  if (g >= gcount[b]) return;
  const int d = threadIdx.x;
  float m = -1e30f;
  for (int c = 0; c < NPART; ++c)
    m = fmaxf(m, pm[((size_t)(bh * NPART + c)) * CG + g]);
  float L = 0.f, acc = 0.f;
  for (int c = 0; c < NPART; ++c) {
    const size_t o = ((size_t)(bh * NPART + c)) * CG + g;
    const float w = __expf(pm[o] - m);
    L = fmaf(w, pl[o], L);
    const float x = __uint_as_float((unsigned)pctx[o * CD + d] << 16);
    acc = fmaf(w, x, acc);
  }
  const int tok = gpos[b * CG + g];
  ctx[((size_t)(bh * CS + tok)) * CD + d] = acc / L;
}

extern "C" void kernel_launch(void* const* d_in, const int* in_sizes, int n_in,
                              void* d_out, int out_size, void* d_ws, size_t ws_size,
                              hipStream_t stream) {
  const float* q = (const float*)d_in[0];
  const float* k = (const float*)d_in[1];
  const float* v = (const float*)d_in[2];
  const int* mask = (const int*)d_in[3];

  float* ctx = (float*)d_out;
  float* probs = ctx + (size_t)CBH * CS * CD;

  char* ws = (char*)d_ws;
  int* gpos = (int*)ws;                                  // 512 B
  int* gcount = (int*)(ws + 512);                        // 512 B
  float* pm = (float*)(ws + 1024);                       // CBH*NPART*CG f32
  float* pl = pm + (size_t)CBH * NPART * CG;             // CBH*NPART*CG f32
  unsigned short* pctx =
      (unsigned short*)(pl + (size_t)CBH * NPART * CG);  // CBH*NPART*CG*CD bf16

  k_setup<<<dim3(CB), dim3(64), 0, stream>>>(mask, gpos, gcount);
  k_main<<<dim3(NW1 + G2NCH, CBH), dim3(256), 0, stream>>>(
      q, k, v, gpos, gcount, ctx, probs, pm, pl, pctx);
  k_combine<<<dim3(CG, CBH), dim3(64), 0, stream>>>(
      pm, pl, pctx, gpos, gcount, ctx);
}

// Round 8
// 73.353 us; speedup vs baseline: 1.0471x; 1.0471x over previous
//
#include <hip/hip_runtime.h>
#include <cstddef>

constexpr int CB  = 2;
constexpr int CH  = 16;
constexpr int CS  = 4096;
constexpr int CD  = 64;
constexpr int CG  = 64;
constexpr int CBH = CB * CH;
constexpr int NW1   = CS / 128;   // part-1 windows per bh (32)
constexpr int G2NCH = 32;         // part-2 128-key windows per bh
constexpr int NPART = G2NCH * 2;  // partials per (bh,q): window x key-half

typedef float  f32x16 __attribute__((ext_vector_type(16)));
typedef short  short8 __attribute__((ext_vector_type(8)));
typedef float  fvec4  __attribute__((ext_vector_type(4)));

union U8 { unsigned u[4]; short8 s; };

__device__ __forceinline__ unsigned short f2bf(float x) {
  unsigned u = __float_as_uint(x);
  unsigned r = u + 0x7fffu + ((u >> 16) & 1u);  // RNE
  return (unsigned short)(r >> 16);
}
__device__ __forceinline__ unsigned pk2(float lo, float hi) {
  return (unsigned)f2bf(lo) | ((unsigned)f2bf(hi) << 16);
}
__device__ __forceinline__ f32x16 zero16() {
  f32x16 z;
#pragma unroll
  for (int i = 0; i < 16; ++i) z[i] = 0.f;
  return z;
}

// P -> MFMA-A fragment relayout for one 16-key slot (exchange across lane^32).
#define MK_PA(dst, hi_, a0,a1,a2,a3,a4,a5,a6,a7)                         \
  {                                                                      \
    unsigned x0 = pk2(a0, a1), x1 = pk2(a2, a3);                         \
    unsigned y0 = pk2(a4, a5), y1 = pk2(a6, a7);                         \
    unsigned t0 = (unsigned)__shfl_xor((int)((hi_) ? x0 : y0), 32);      \
    if (hi_) x0 = t0; else y0 = t0;                                      \
    unsigned t1 = (unsigned)__shfl_xor((int)((hi_) ? x1 : y1), 32);      \
    if (hi_) x1 = t1; else y1 = t1;                                      \
    U8 w_; w_.u[0] = x0; w_.u[1] = x1; w_.u[2] = y0; w_.u[3] = y1;       \
    dst = w_.s;                                                          \
  }

// ---------------------------------------------------------------------------
__global__ void k_setup(const int* __restrict__ mask,
                        int* __restrict__ gpos, int* __restrict__ gcount) {
  const int b = blockIdx.x;
  const int t = threadIdx.x;  // 64
  __shared__ int cnt[64];
  if (t < CG) gpos[b * CG + t] = 0;
  const int span = CS / 64;
  const int base = b * CS + t * span;
  int c = 0;
  for (int i = 0; i < span; ++i) c += (mask[base + i] > 0) ? 1 : 0;
  cnt[t] = c;
  __syncthreads();
  int pre = 0;
  for (int j = 0; j < t; ++j) pre += cnt[j];
  for (int i = 0; i < span; ++i) {
    if (mask[base + i] > 0) {
      if (pre < CG) gpos[b * CG + pre] = t * span + i;
      ++pre;
    }
  }
  if (t == 63) gcount[b] = (pre < CG) ? pre : CG;
}

// ---------------------------------------------------------------------------
// Fused main kernel, single-exposed-latency schedule:
//   issue ALL global loads (q frags, gpos entries, staged K/V rows) into
//   registers first; convert+ds_write; ONE barrier; compute.
// blockIdx.x < NW1 : part-1 (128 q-rows x 64 global KVs), 16 KB LDS.
// else             : part-2 (64 global q x one 128-key window, waves =
//                    q-tile x key-half, r6-verified mapping), 32 KB LDS.
// ---------------------------------------------------------------------------
struct __align__(16) SMemP1 { short sK[64 * 64]; short sVT[64 * 64]; };
struct __align__(16) SMemP2 { short sK2[2][64 * 64]; short sVT2[2][64 * 64]; };
union __align__(16) SMem { SMemP1 p1; SMemP2 p2; };

__global__ __launch_bounds__(256, 2) void k_main(
    const float* __restrict__ q, const float* __restrict__ k,
    const float* __restrict__ v,
    const int* __restrict__ gpos, const int* __restrict__ gcount,
    float* __restrict__ ctx, float* __restrict__ probs,
    float* __restrict__ pm, float* __restrict__ pl,
    unsigned short* __restrict__ pctx) {
  __shared__ SMem sm;
  const int bh = blockIdx.y, b = bh / CH, t = threadIdx.x;
  const int lane = t & 63, wv = t >> 6;
  const int hi = lane >> 5, ql = lane & 31;
  const unsigned kswz = (unsigned)((ql & 7) << 4);

  if (blockIdx.x < NW1) {
    // ------------------------------ part 1 ------------------------------
    // A) q fragment loads (independent of everything)
    const int qrow = blockIdx.x * 128 + wv * 32 + ql;
    const float* qr = q + ((size_t)(bh * CS + qrow)) * CD + hi * 8;
    fvec4 qa[8];
#pragma unroll
    for (int s = 0; s < 4; ++s) {
      qa[2 * s]     = *(const fvec4*)(qr + s * 16);
      qa[2 * s + 1] = *(const fvec4*)(qr + s * 16 + 4);
    }
    const int gc = gcount[b];  // tiny, L2-hot

    // B) staged loads -> registers (gpos direct loads, L2-hot)
    if (t < 128) {  // K rows
      const int row = t >> 1, c0 = (t & 1) * 32;
      const int grow = gpos[b * CG + row];
      const float* src = k + ((size_t)(bh * CS + grow)) * CD + c0;
      fvec4 ra[8];
#pragma unroll
      for (int i = 0; i < 4; ++i) {
        ra[2 * i]     = *(const fvec4*)(src + i * 8);
        ra[2 * i + 1] = *(const fvec4*)(src + i * 8 + 4);
      }
      const unsigned swz = (unsigned)((row & 7) << 4);
      char* rb = (char*)sm.p1.sK + row * 128;
#pragma unroll
      for (int i = 0; i < 4; ++i) {
        U8 w;
        w.u[0] = pk2(ra[2 * i][0], ra[2 * i][1]);
        w.u[1] = pk2(ra[2 * i][2], ra[2 * i][3]);
        w.u[2] = pk2(ra[2 * i + 1][0], ra[2 * i + 1][1]);
        w.u[3] = pk2(ra[2 * i + 1][2], ra[2 * i + 1][3]);
        *(short8*)(rb + (((unsigned)(c0 * 2 + i * 16)) ^ swz)) = w.s;
      }
    } else {  // V rows, transposed into sVT[d][key]
      const int u = t - 128;
      const int kg = u >> 4, cg = u & 15;
      int gi[8];
#pragma unroll
      for (int i = 0; i < 8; ++i) gi[i] = gpos[b * CG + 8 * kg + i];
      fvec4 rv[8];
#pragma unroll
      for (int i = 0; i < 8; ++i)
        rv[i] = *(const fvec4*)(v + ((size_t)(bh * CS + gi[i])) * CD + 4 * cg);
#pragma unroll
      for (int c = 0; c < 4; ++c) {
        const int row = 4 * cg + c;
        U8 w;
        w.u[0] = pk2(rv[0][c], rv[1][c]); w.u[1] = pk2(rv[2][c], rv[3][c]);
        w.u[2] = pk2(rv[4][c], rv[5][c]); w.u[3] = pk2(rv[6][c], rv[7][c]);
        *(short8*)((char*)sm.p1.sVT + row * 128 +
                   (((unsigned)(16 * kg)) ^ ((unsigned)((row & 7) << 4)))) = w.s;
      }
    }
    __syncthreads();

    // C) convert q (scaled), compute
    short8 qf[4];
#pragma unroll
    for (int s = 0; s < 4; ++s) {
      U8 w;
      w.u[0] = pk2(qa[2 * s][0] * 0.125f, qa[2 * s][1] * 0.125f);
      w.u[1] = pk2(qa[2 * s][2] * 0.125f, qa[2 * s][3] * 0.125f);
      w.u[2] = pk2(qa[2 * s + 1][0] * 0.125f, qa[2 * s + 1][1] * 0.125f);
      w.u[3] = pk2(qa[2 * s + 1][2] * 0.125f, qa[2 * s + 1][3] * 0.125f);
      qf[s] = w.s;
    }

    f32x16 acc0 = zero16(), acc1 = zero16();
#pragma unroll
    for (int s = 0; s < 4; ++s) {
      const unsigned off = ((unsigned)(32 * s + 16 * hi)) ^ kswz;
      short8 k0 = *(const short8*)((char*)sm.p1.sK + ql * 128 + off);
      acc0 = __builtin_amdgcn_mfma_f32_32x32x16_bf16(k0, qf[s], acc0, 0, 0, 0);
      short8 k1 = *(const short8*)((char*)sm.p1.sK + (32 + ql) * 128 + off);
      acc1 = __builtin_amdgcn_mfma_f32_32x32x16_bf16(k1, qf[s], acc1, 0, 0, 0);
    }

    float p0[16], p1[16];
    float m = -1e30f;
#pragma unroll
    for (int r = 0; r < 16; ++r) {
      const int key0 = (r & 3) + 8 * (r >> 2) + 4 * hi;
      float x0 = (key0 < gc) ? acc0[r] : -1e30f;
      float x1 = (key0 + 32 < gc) ? acc1[r] : -1e30f;
      p0[r] = x0; p1[r] = x1;
      m = fmaxf(m, fmaxf(x0, x1));
    }
    m = fmaxf(m, __shfl_xor(m, 32));
    float ls = 0.f;
#pragma unroll
    for (int r = 0; r < 16; ++r) {
      p0[r] = __expf(p0[r] - m); ls += p0[r];
      p1[r] = __expf(p1[r] - m); ls += p1[r];
    }
    ls += __shfl_xor(ls, 32);
    const float inv = 1.0f / ls;
#pragma unroll
    for (int r = 0; r < 16; ++r) { p0[r] *= inv; p1[r] *= inv; }

    float* prow = probs + ((size_t)(bh * CS + qrow)) * CG;
#pragma unroll
    for (int g4 = 0; g4 < 4; ++g4) {
      fvec4 o0 = {p0[4 * g4], p0[4 * g4 + 1], p0[4 * g4 + 2], p0[4 * g4 + 3]};
      fvec4 o1 = {p1[4 * g4], p1[4 * g4 + 1], p1[4 * g4 + 2], p1[4 * g4 + 3]};
      *(fvec4*)(prow + 8 * g4 + 4 * hi) = o0;
      *(fvec4*)(prow + 8 * g4 + 4 * hi + 32) = o1;
    }

    short8 pa0, pa1, pa2, pa3;
    MK_PA(pa0, hi, p0[0], p0[1], p0[2], p0[3], p0[4], p0[5], p0[6], p0[7]);
    MK_PA(pa1, hi, p0[8], p0[9], p0[10], p0[11], p0[12], p0[13], p0[14], p0[15]);
    MK_PA(pa2, hi, p1[0], p1[1], p1[2], p1[3], p1[4], p1[5], p1[6], p1[7]);
    MK_PA(pa3, hi, p1[8], p1[9], p1[10], p1[11], p1[12], p1[13], p1[14], p1[15]);

    f32x16 oc0 = zero16(), oc1 = zero16();
#pragma unroll
    for (int s = 0; s < 4; ++s) {
      const short8 pas = (s == 0) ? pa0 : (s == 1) ? pa1 : (s == 2) ? pa2 : pa3;
      const unsigned off = ((unsigned)(32 * s + 16 * hi)) ^ kswz;
      short8 v0 = *(const short8*)((char*)sm.p1.sVT + ql * 128 + off);
      oc0 = __builtin_amdgcn_mfma_f32_32x32x16_bf16(pas, v0, oc0, 0, 0, 0);
      short8 v1 = *(const short8*)((char*)sm.p1.sVT + (32 + ql) * 128 + off);
      oc1 = __builtin_amdgcn_mfma_f32_32x32x16_bf16(pas, v1, oc1, 0, 0, 0);
    }

    float* cb = ctx + ((size_t)(bh * CS + blockIdx.x * 128 + wv * 32)) * CD;
#pragma unroll
    for (int r = 0; r < 16; ++r) {
      const int qr2 = (r & 3) + 8 * (r >> 2) + 4 * hi;
      cb[(size_t)qr2 * CD + ql] = oc0[r];
      cb[(size_t)qr2 * CD + 32 + ql] = oc1[r];
    }
  } else {
    // ------------------------------ part 2 ------------------------------
    const int bx = blockIdx.x - NW1;
    const int kwin = bx * 128;
    const int qt = wv & 1, kh = wv >> 1;
    const int qslot = qt * 32 + ql;

    // A) q fragment loads (gpos direct load first, L2-hot)
    const int gq = gpos[b * CG + qslot];
    const float* qr = q + ((size_t)(bh * CS + gq)) * CD + hi * 8;
    fvec4 qa[8];
#pragma unroll
    for (int s = 0; s < 4; ++s) {
      qa[2 * s]     = *(const fvec4*)(qr + s * 16);
      qa[2 * s + 1] = *(const fvec4*)(qr + s * 16 + 4);
    }

    // B) staged loads for BOTH 64-key halves -> registers, then LDS
    if (t < 128) {  // K rows: half-row per thread per half
      const int row = t >> 1, c0 = (t & 1) * 32;
      fvec4 ka[2][8];
#pragma unroll
      for (int h = 0; h < 2; ++h) {
        const float* src =
            k + ((size_t)(bh * CS + kwin + h * 64 + row)) * CD + c0;
#pragma unroll
        for (int i = 0; i < 4; ++i) {
          ka[h][2 * i]     = *(const fvec4*)(src + i * 8);
          ka[h][2 * i + 1] = *(const fvec4*)(src + i * 8 + 4);
        }
      }
      const unsigned swz = (unsigned)((row & 7) << 4);
#pragma unroll
      for (int h = 0; h < 2; ++h) {
        char* rb = (char*)sm.p2.sK2[h] + row * 128;
#pragma unroll
        for (int i = 0; i < 4; ++i) {
          U8 w;
          w.u[0] = pk2(ka[h][2 * i][0], ka[h][2 * i][1]);
          w.u[1] = pk2(ka[h][2 * i][2], ka[h][2 * i][3]);
          w.u[2] = pk2(ka[h][2 * i + 1][0], ka[h][2 * i + 1][1]);
          w.u[3] = pk2(ka[h][2 * i + 1][2], ka[h][2 * i + 1][3]);
          *(short8*)(rb + (((unsigned)(c0 * 2 + i * 16)) ^ swz)) = w.s;
        }
      }
    } else {  // V rows, transposed
      const int u = t - 128;
      const int kg = u >> 4, cg = u & 15;
      fvec4 va[2][8];
#pragma unroll
      for (int h = 0; h < 2; ++h)
#pragma unroll
        for (int i = 0; i < 8; ++i)
          va[h][i] = *(const fvec4*)(
              v + ((size_t)(bh * CS + kwin + h * 64 + 8 * kg + i)) * CD + 4 * cg);
#pragma unroll
      for (int h = 0; h < 2; ++h)
#pragma unroll
        for (int c = 0; c < 4; ++c) {
          const int row = 4 * cg + c;
          U8 w;
          w.u[0] = pk2(va[h][0][c], va[h][1][c]);
          w.u[1] = pk2(va[h][2][c], va[h][3][c]);
          w.u[2] = pk2(va[h][4][c], va[h][5][c]);
          w.u[3] = pk2(va[h][6][c], va[h][7][c]);
          *(short8*)((char*)sm.p2.sVT2[h] + row * 128 +
                     (((unsigned)(16 * kg)) ^ ((unsigned)((row & 7) << 4)))) = w.s;
        }
    }
    __syncthreads();

    // C) convert q (scaled), compute over this wave's 64-key half
    short8 qf[4];
#pragma unroll
    for (int s = 0; s < 4; ++s) {
      U8 w;
      w.u[0] = pk2(qa[2 * s][0] * 0.125f, qa[2 * s][1] * 0.125f);
      w.u[1] = pk2(qa[2 * s][2] * 0.125f, qa[2 * s][3] * 0.125f);
      w.u[2] = pk2(qa[2 * s + 1][0] * 0.125f, qa[2 * s + 1][1] * 0.125f);
      w.u[3] = pk2(qa[2 * s + 1][2] * 0.125f, qa[2 * s + 1][3] * 0.125f);
      qf[s] = w.s;
    }

    const char* bK = (const char*)sm.p2.sK2[kh];
    const char* bVT = (const char*)sm.p2.sVT2[kh];

    f32x16 acc0 = zero16(), acc1 = zero16();
#pragma unroll
    for (int s = 0; s < 4; ++s) {
      const unsigned off = ((unsigned)(32 * s + 16 * hi)) ^ kswz;
      short8 k0 = *(const short8*)(bK + ql * 128 + off);
      acc0 = __builtin_amdgcn_mfma_f32_32x32x16_bf16(k0, qf[s], acc0, 0, 0, 0);
      short8 k1 = *(const short8*)(bK + (32 + ql) * 128 + off);
      acc1 = __builtin_amdgcn_mfma_f32_32x32x16_bf16(k1, qf[s], acc1, 0, 0, 0);
    }

    float p0[16], p1[16];
    float m = -1e30f;
#pragma unroll
    for (int r = 0; r < 16; ++r) {
      p0[r] = acc0[r]; p1[r] = acc1[r];
      m = fmaxf(m, fmaxf(p0[r], p1[r]));
    }
    m = fmaxf(m, __shfl_xor(m, 32));
    float ls = 0.f;
#pragma unroll
    for (int r = 0; r < 16; ++r) {
      p0[r] = __expf(p0[r] - m); ls += p0[r];
      p1[r] = __expf(p1[r] - m); ls += p1[r];
    }
    ls += __shfl_xor(ls, 32);

    short8 pa0, pa1, pa2, pa3;
    MK_PA(pa0, hi, p0[0], p0[1], p0[2], p0[3], p0[4], p0[5], p0[6], p0[7]);
    MK_PA(pa1, hi, p0[8], p0[9], p0[10], p0[11], p0[12], p0[13], p0[14], p0[15]);
    MK_PA(pa2, hi, p1[0], p1[1], p1[2], p1[3], p1[4], p1[5], p1[6], p1[7]);
    MK_PA(pa3, hi, p1[8], p1[9], p1[10], p1[11], p1[12], p1[13], p1[14], p1[15]);

    f32x16 oc0 = zero16(), oc1 = zero16();
#pragma unroll
    for (int s = 0; s < 4; ++s) {
      const short8 pas = (s == 0) ? pa0 : (s == 1) ? pa1 : (s == 2) ? pa2 : pa3;
      const unsigned off = ((unsigned)(32 * s + 16 * hi)) ^ kswz;
      short8 v0 = *(const short8*)(bVT + ql * 128 + off);
      oc0 = __builtin_amdgcn_mfma_f32_32x32x16_bf16(pas, v0, oc0, 0, 0, 0);
      short8 v1 = *(const short8*)(bVT + (32 + ql) * 128 + off);
      oc1 = __builtin_amdgcn_mfma_f32_32x32x16_bf16(pas, v1, oc1, 0, 0, 0);
    }

    const int part = bx * 2 + kh;
    if (hi == 0) {
      const size_t o = ((size_t)(bh * NPART + part)) * CG + qslot;
      pm[o] = m;
      pl[o] = ls;
    }
    unsigned short* po =
        pctx + (((size_t)(bh * NPART + part)) * CG + qt * 32) * CD;
#pragma unroll
    for (int r = 0; r < 16; ++r) {
      const int qr2 = (r & 3) + 8 * (r >> 2) + 4 * hi;
      po[(size_t)qr2 * CD + ql] = f2bf(oc0[r]);
      po[(size_t)qr2 * CD + 32 + ql] = f2bf(oc1[r]);
    }
  }
}

// ---------------------------------------------------------------------------
__global__ __launch_bounds__(64) void k_combine(
    const float* __restrict__ pm, const float* __restrict__ pl,
    const unsigned short* __restrict__ pctx,
    const int* __restrict__ gpos, const int* __restrict__ gcount,
    float* __restrict__ ctx) {
  const int g = blockIdx.x;
  const int bh = blockIdx.y;
  const int b = bh / CH;
  if (g >= gcount[b]) return;
  const int d = threadIdx.x;
  float m = -1e30f;
  for (int c = 0; c < NPART; ++c)
    m = fmaxf(m, pm[((size_t)(bh * NPART + c)) * CG + g]);
  float L = 0.f, acc = 0.f;
  for (int c = 0; c < NPART; ++c) {
    const size_t o = ((size_t)(bh * NPART + c)) * CG + g;
    const float w = __expf(pm[o] - m);
    L = fmaf(w, pl[o], L);
    const float x = __uint_as_float((unsigned)pctx[o * CD + d] << 16);
    acc = fmaf(w, x, acc);
  }
  const int tok = gpos[b * CG + g];
  ctx[((size_t)(bh * CS + tok)) * CD + d] = acc / L;
}

extern "C" void kernel_launch(void* const* d_in, const int* in_sizes, int n_in,
                              void* d_out, int out_size, void* d_ws, size_t ws_size,
                              hipStream_t stream) {
  const float* q = (const float*)d_in[0];
  const float* k = (const float*)d_in[1];
  const float* v = (const float*)d_in[2];
  const int* mask = (const int*)d_in[3];

  float* ctx = (float*)d_out;
  float* probs = ctx + (size_t)CBH * CS * CD;

  char* ws = (char*)d_ws;
  int* gpos = (int*)ws;                                  // 512 B
  int* gcount = (int*)(ws + 512);                        // 512 B
  float* pm = (float*)(ws + 1024);                       // CBH*NPART*CG f32
  float* pl = pm + (size_t)CBH * NPART * CG;             // CBH*NPART*CG f32
  unsigned short* pctx =
      (unsigned short*)(pl + (size_t)CBH * NPART * CG);  // CBH*NPART*CG*CD bf16

  k_setup<<<dim3(CB), dim3(64), 0, stream>>>(mask, gpos, gcount);
  k_main<<<dim3(NW1 + G2NCH, CBH), dim3(256), 0, stream>>>(
      q, k, v, gpos, gcount, ctx, probs, pm, pl, pctx);
  k_combine<<<dim3(CG, CBH), dim3(64), 0, stream>>>(
      pm, pl, pctx, gpos, gcount, ctx);
}

// Round 10
// 64.839 us; speedup vs baseline: 1.1846x; 1.1313x over previous
//
#include <hip/hip_runtime.h>
#include <cstddef>

constexpr int CB  = 2;
constexpr int CH  = 16;
constexpr int CS  = 4096;
constexpr int CD  = 64;
constexpr int CG  = 64;
constexpr int CBH = CB * CH;
constexpr int NW1   = 64;         // part-1 blocks per bh (64 q-rows each)
constexpr int G2N   = 64;         // part-2 blocks per bh (64-key half-window)
constexpr int NPART = 64;         // same partial contract as r8 (part = key/64)

typedef float  f32x16 __attribute__((ext_vector_type(16)));
typedef short  short8 __attribute__((ext_vector_type(8)));
typedef float  fvec4  __attribute__((ext_vector_type(4)));

union U8 { unsigned u[4]; short8 s; };

__device__ __forceinline__ unsigned short f2bf(float x) {
  unsigned u = __float_as_uint(x);
  unsigned r = u + 0x7fffu + ((u >> 16) & 1u);  // RNE
  return (unsigned short)(r >> 16);
}
__device__ __forceinline__ unsigned pk2(float lo, float hi) {
  return (unsigned)f2bf(lo) | ((unsigned)f2bf(hi) << 16);
}
__device__ __forceinline__ f32x16 zero16() {
  f32x16 z;
#pragma unroll
  for (int i = 0; i < 16; ++i) z[i] = 0.f;
  return z;
}

// P -> MFMA-A fragment relayout for one 16-key slot (exchange across lane^32).
#define MK_PA(dst, hi_, a0,a1,a2,a3,a4,a5,a6,a7)                         \
  {                                                                      \
    unsigned x0 = pk2(a0, a1), x1 = pk2(a2, a3);                         \
    unsigned y0 = pk2(a4, a5), y1 = pk2(a6, a7);                         \
    unsigned t0 = (unsigned)__shfl_xor((int)((hi_) ? x0 : y0), 32);      \
    if (hi_) x0 = t0; else y0 = t0;                                      \
    unsigned t1 = (unsigned)__shfl_xor((int)((hi_) ? x1 : y1), 32);      \
    if (hi_) x1 = t1; else y1 = t1;                                      \
    U8 w_; w_.u[0] = x0; w_.u[1] = x1; w_.u[2] = y0; w_.u[3] = y1;       \
    dst = w_.s;                                                          \
  }

// ---------------------------------------------------------------------------
__global__ void k_setup(const int* __restrict__ mask,
                        int* __restrict__ gpos, int* __restrict__ gcount) {
  const int b = blockIdx.x;
  const int t = threadIdx.x;  // 64
  __shared__ int cnt[64];
  if (t < CG) gpos[b * CG + t] = 0;
  const int span = CS / 64;
  const int base = b * CS + t * span;
  int c = 0;
  for (int i = 0; i < span; ++i) c += (mask[base + i] > 0) ? 1 : 0;
  cnt[t] = c;
  __syncthreads();
  int pre = 0;
  for (int j = 0; j < t; ++j) pre += cnt[j];
  for (int i = 0; i < span; ++i) {
    if (mask[base + i] > 0) {
      if (pre < CG) gpos[b * CG + pre] = t * span + i;
      ++pre;
    }
  }
  if (t == 63) gcount[b] = (pre < CG) ? pre : CG;
}

// ---------------------------------------------------------------------------
// Fused main kernel: 128 threads (2 waves), 16 KB LDS -> high residency.
// blockIdx.x < NW1 : part-1, block owns 64 q-rows (wave = 32 q) x 64 gKV.
// else             : part-2, block owns one 64-key half-window; waves are the
//                    two q-tiles (32 global q each). part = bx (r8 contract).
// Staging: t<64 stages K row t; t>=64 stages V transposed (8 rows x 8 cols).
// ---------------------------------------------------------------------------
struct __align__(16) SMem { short sK[64 * 64]; short sVT[64 * 64]; };

__global__ __launch_bounds__(128, 4) void k_main(
    const float* __restrict__ q, const float* __restrict__ k,
    const float* __restrict__ v,
    const int* __restrict__ gpos, const int* __restrict__ gcount,
    float* __restrict__ ctx, float* __restrict__ probs,
    float* __restrict__ pm, float* __restrict__ pl,
    unsigned short* __restrict__ pctx) {
  __shared__ SMem sm;
  const int bh = blockIdx.y, b = bh / CH, t = threadIdx.x;
  const int lane = t & 63, wv = t >> 6;           // 2 waves
  const int hi = lane >> 5, ql = lane & 31;
  const unsigned kswz = (unsigned)((ql & 7) << 4);
  const bool isP1 = (blockIdx.x < NW1);
  const int bx = isP1 ? blockIdx.x : (blockIdx.x - NW1);
  const int kwin = bx * 64;  // part-2 key window base

  // ---- A) q fragment prefetch (independent of staging) ----
  int qrow;     // part-1: row in [0,CS); part-2: gathered token row
  if (isP1) {
    qrow = bx * 64 + wv * 32 + ql;
  } else {
    qrow = gpos[b * CG + wv * 32 + ql];
  }
  const float* qr = q + ((size_t)(bh * CS + qrow)) * CD + hi * 8;
  fvec4 qa[8];
#pragma unroll
  for (int s = 0; s < 4; ++s) {
    qa[2 * s]     = *(const fvec4*)(qr + s * 16);
    qa[2 * s + 1] = *(const fvec4*)(qr + s * 16 + 4);
  }

  // ---- B) stage K / V^T tiles (row source differs by role) ----
  if (t < 64) {  // K row t -> sK[t][*]
    const int row = t;
    const int srow = isP1 ? gpos[b * CG + row] : (kwin + row);
    const float* src = k + ((size_t)(bh * CS + srow)) * CD;
    fvec4 ka[16];
#pragma unroll
    for (int i = 0; i < 8; ++i) {
      ka[2 * i]     = *(const fvec4*)(src + i * 8);
      ka[2 * i + 1] = *(const fvec4*)(src + i * 8 + 4);
    }
    const unsigned swz = (unsigned)((row & 7) << 4);
    char* rb = (char*)sm.sK + row * 128;
#pragma unroll
    for (int i = 0; i < 8; ++i) {
      U8 w;
      w.u[0] = pk2(ka[2 * i][0], ka[2 * i][1]);
      w.u[1] = pk2(ka[2 * i][2], ka[2 * i][3]);
      w.u[2] = pk2(ka[2 * i + 1][0], ka[2 * i + 1][1]);
      w.u[3] = pk2(ka[2 * i + 1][2], ka[2 * i + 1][3]);
      *(short8*)(rb + (((unsigned)(i * 16)) ^ swz)) = w.s;
    }
  } else {  // V rows (8 keys) x 8 d-cols -> sVT[d][key]
    const int u = t - 64;
    const int kg = u >> 3, cg = u & 7;
    fvec4 va[8], vb[8];
#pragma unroll
    for (int i = 0; i < 8; ++i) {
      const int srow = isP1 ? gpos[b * CG + 8 * kg + i] : (kwin + 8 * kg + i);
      const float* sv = v + ((size_t)(bh * CS + srow)) * CD + 8 * cg;
      va[i] = *(const fvec4*)sv;
      vb[i] = *(const fvec4*)(sv + 4);
    }
#pragma unroll
    for (int c = 0; c < 8; ++c) {
      const int row = 8 * cg + c;
      float vals[8];
#pragma unroll
      for (int i = 0; i < 8; ++i)
        vals[i] = (c < 4) ? va[i][c & 3] : vb[i][c & 3];
      U8 w;
      w.u[0] = pk2(vals[0], vals[1]); w.u[1] = pk2(vals[2], vals[3]);
      w.u[2] = pk2(vals[4], vals[5]); w.u[3] = pk2(vals[6], vals[7]);
      *(short8*)((char*)sm.sVT + row * 128 +
                 (((unsigned)(16 * kg)) ^ ((unsigned)((row & 7) << 4)))) = w.s;
    }
  }
  __syncthreads();

  // ---- C) convert q (scaled) ----
  short8 qf[4];
#pragma unroll
  for (int s = 0; s < 4; ++s) {
    U8 w;
    w.u[0] = pk2(qa[2 * s][0] * 0.125f, qa[2 * s][1] * 0.125f);
    w.u[1] = pk2(qa[2 * s][2] * 0.125f, qa[2 * s][3] * 0.125f);
    w.u[2] = pk2(qa[2 * s + 1][0] * 0.125f, qa[2 * s + 1][1] * 0.125f);
    w.u[3] = pk2(qa[2 * s + 1][2] * 0.125f, qa[2 * s + 1][3] * 0.125f);
    qf[s] = w.s;
  }

  // ---- D) QK^T (swapped): acc0 keys 0..31, acc1 keys 32..63 ----
  f32x16 acc0 = zero16(), acc1 = zero16();
#pragma unroll
  for (int s = 0; s < 4; ++s) {
    const unsigned off = ((unsigned)(32 * s + 16 * hi)) ^ kswz;
    short8 k0 = *(const short8*)((char*)sm.sK + ql * 128 + off);
    acc0 = __builtin_amdgcn_mfma_f32_32x32x16_bf16(k0, qf[s], acc0, 0, 0, 0);
    short8 k1 = *(const short8*)((char*)sm.sK + (32 + ql) * 128 + off);
    acc1 = __builtin_amdgcn_mfma_f32_32x32x16_bf16(k1, qf[s], acc1, 0, 0, 0);
  }

  // ---- E) softmax ----
  float e0[16], e1[16];
  float m = -1e30f;
  if (isP1) {
    const int gc = gcount[b];
#pragma unroll
    for (int r = 0; r < 16; ++r) {
      const int key0 = (r & 3) + 8 * (r >> 2) + 4 * hi;
      float x0 = (key0 < gc) ? acc0[r] : -1e30f;
      float x1 = (key0 + 32 < gc) ? acc1[r] : -1e30f;
      e0[r] = x0; e1[r] = x1;
      m = fmaxf(m, fmaxf(x0, x1));
    }
  } else {
#pragma unroll
    for (int r = 0; r < 16; ++r) {
      e0[r] = acc0[r]; e1[r] = acc1[r];
      m = fmaxf(m, fmaxf(e0[r], e1[r]));
    }
  }
  m = fmaxf(m, __shfl_xor(m, 32));
  float ls = 0.f;
#pragma unroll
  for (int r = 0; r < 16; ++r) {
    e0[r] = __expf(e0[r] - m); ls += e0[r];
    e1[r] = __expf(e1[r] - m); ls += e1[r];
  }
  ls += __shfl_xor(ls, 32);

  if (isP1) {  // normalize now; write probs
    const float inv = 1.0f / ls;
#pragma unroll
    for (int r = 0; r < 16; ++r) { e0[r] *= inv; e1[r] *= inv; }
    const int qout = bx * 64 + wv * 32 + ql;
    float* prow = probs + ((size_t)(bh * CS + qout)) * CG;
#pragma unroll
    for (int g4 = 0; g4 < 4; ++g4) {
      fvec4 o0 = {e0[4 * g4], e0[4 * g4 + 1], e0[4 * g4 + 2], e0[4 * g4 + 3]};
      fvec4 o1 = {e1[4 * g4], e1[4 * g4 + 1], e1[4 * g4 + 2], e1[4 * g4 + 3]};
      *(fvec4*)(prow + 8 * g4 + 4 * hi) = o0;
      *(fvec4*)(prow + 8 * g4 + 4 * hi + 32) = o1;
    }
  }

  // ---- F) P -> A fragments; PV ----
  short8 pa0, pa1, pa2, pa3;
  MK_PA(pa0, hi, e0[0], e0[1], e0[2], e0[3], e0[4], e0[5], e0[6], e0[7]);
  MK_PA(pa1, hi, e0[8], e0[9], e0[10], e0[11], e0[12], e0[13], e0[14], e0[15]);
  MK_PA(pa2, hi, e1[0], e1[1], e1[2], e1[3], e1[4], e1[5], e1[6], e1[7]);
  MK_PA(pa3, hi, e1[8], e1[9], e1[10], e1[11], e1[12], e1[13], e1[14], e1[15]);

  f32x16 oc0 = zero16(), oc1 = zero16();
#pragma unroll
  for (int s = 0; s < 4; ++s) {
    const short8 pas = (s == 0) ? pa0 : (s == 1) ? pa1 : (s == 2) ? pa2 : pa3;
    const unsigned off = ((unsigned)(32 * s + 16 * hi)) ^ kswz;
    short8 v0 = *(const short8*)((char*)sm.sVT + ql * 128 + off);
    oc0 = __builtin_amdgcn_mfma_f32_32x32x16_bf16(pas, v0, oc0, 0, 0, 0);
    short8 v1 = *(const short8*)((char*)sm.sVT + (32 + ql) * 128 + off);
    oc1 = __builtin_amdgcn_mfma_f32_32x32x16_bf16(pas, v1, oc1, 0, 0, 0);
  }

  // ---- G) outputs ----
  if (isP1) {
    float* cb = ctx + ((size_t)(bh * CS + bx * 64 + wv * 32)) * CD;
#pragma unroll
    for (int r = 0; r < 16; ++r) {
      const int qr2 = (r & 3) + 8 * (r >> 2) + 4 * hi;
      cb[(size_t)qr2 * CD + ql] = oc0[r];
      cb[(size_t)qr2 * CD + 32 + ql] = oc1[r];
    }
  } else {
    const int qslot = wv * 32 + ql;
    if (hi == 0) {
      const size_t o = ((size_t)(bh * NPART + bx)) * CG + qslot;
      pm[o] = m;
      pl[o] = ls;
    }
    unsigned short* po =
        pctx + (((size_t)(bh * NPART + bx)) * CG + wv * 32) * CD;
#pragma unroll
    for (int r = 0; r < 16; ++r) {
      const int qr2 = (r & 3) + 8 * (r >> 2) + 4 * hi;
      po[(size_t)qr2 * CD + ql] = f2bf(oc0[r]);
      po[(size_t)qr2 * CD + 32 + ql] = f2bf(oc1[r]);
    }
  }
}

// ---------------------------------------------------------------------------
// Combine: 256 threads = 4 c-groups x 64 d. 16-deep chains + LDS reduction.
// ---------------------------------------------------------------------------
__global__ __launch_bounds__(256) void k_combine(
    const float* __restrict__ pm, const float* __restrict__ pl,
    const unsigned short* __restrict__ pctx,
    const int* __restrict__ gpos, const int* __restrict__ gcount,
    float* __restrict__ ctx) {
  const int g = blockIdx.x;
  const int bh = blockIdx.y;
  const int b = bh / CH;
  if (g >= gcount[b]) return;
  const int t = threadIdx.x;
  const int cg = t >> 6, d = t & 63;
  __shared__ float smax[4];
  __shared__ float sl[4];
  __shared__ float sacc[4][64];

  float lm = -1e30f;
#pragma unroll
  for (int j = 0; j < 16; ++j) {
    const int c = cg * 16 + j;
    lm = fmaxf(lm, pm[((size_t)(bh * NPART + c)) * CG + g]);
  }
  if (d == 0) smax[cg] = lm;  // lm uniform across the wave (no d dependence)
  __syncthreads();
  const float m = fmaxf(fmaxf(smax[0], smax[1]), fmaxf(smax[2], smax[3]));

  float L = 0.f, acc = 0.f;
#pragma unroll
  for (int j = 0; j < 16; ++j) {
    const int c = cg * 16 + j;
    const size_t o = ((size_t)(bh * NPART + c)) * CG + g;
    const float w = __expf(pm[o] - m);
    L = fmaf(w, pl[o], L);
    const float x = __uint_as_float((unsigned)pctx[o * CD + d] << 16);
    acc = fmaf(w, x, acc);
  }
  sacc[cg][d] = acc;
  if (d == 0) sl[cg] = L;
  __syncthreads();
  if (cg == 0) {
    const float A = sacc[0][d] + sacc[1][d] + sacc[2][d] + sacc[3][d];
    const float Lt = sl[0] + sl[1] + sl[2] + sl[3];
    const int tok = gpos[b * CG + g];
    ctx[((size_t)(bh * CS + tok)) * CD + d] = A / Lt;
  }
}

extern "C" void kernel_launch(void* const* d_in, const int* in_sizes, int n_in,
                              void* d_out, int out_size, void* d_ws, size_t ws_size,
                              hipStream_t stream) {
  const float* q = (const float*)d_in[0];
  const float* k = (const float*)d_in[1];
  const float* v = (const float*)d_in[2];
  const int* mask = (const int*)d_in[3];

  float* ctx = (float*)d_out;
  float* probs = ctx + (size_t)CBH * CS * CD;

  char* ws = (char*)d_ws;
  int* gpos = (int*)ws;                                  // 512 B
  int* gcount = (int*)(ws + 512);                        // 512 B
  float* pm = (float*)(ws + 1024);                       // CBH*NPART*CG f32
  float* pl = pm + (size_t)CBH * NPART * CG;             // CBH*NPART*CG f32
  unsigned short* pctx =
      (unsigned short*)(pl + (size_t)CBH * NPART * CG);  // CBH*NPART*CG*CD bf16

  k_setup<<<dim3(CB), dim3(64), 0, stream>>>(mask, gpos, gcount);
  k_main<<<dim3(NW1 + G2N, CBH), dim3(128), 0, stream>>>(
      q, k, v, gpos, gcount, ctx, probs, pm, pl, pctx);
  k_combine<<<dim3(CG, CBH), dim3(256), 0, stream>>>(
      pm, pl, pctx, gpos, gcount, ctx);
}

// Round 12
// 58.735 us; speedup vs baseline: 1.3078x; 1.1039x over previous
//
#include <hip/hip_runtime.h>
#include <cstddef>

constexpr int CB  = 2;
constexpr int CH  = 16;
constexpr int CS  = 4096;
constexpr int CD  = 64;
constexpr int CG  = 64;
constexpr int CBH = CB * CH;
constexpr int NS1 = 8;            // part-1 splits per bh (4 q-windows of 128)
constexpr int NS2 = 8;            // part-2 splits per bh (4 key-windows of 128)
constexpr int NPART = 64;         // r8/r10 contract: (window)*2 + key-half

typedef float  f32x16 __attribute__((ext_vector_type(16)));
typedef short  short8 __attribute__((ext_vector_type(8)));
typedef float  fvec4  __attribute__((ext_vector_type(4)));

union U8 { unsigned u[4]; short8 s; };

__device__ __forceinline__ unsigned short f2bf(float x) {
  unsigned u = __float_as_uint(x);
  unsigned r = u + 0x7fffu + ((u >> 16) & 1u);  // RNE
  return (unsigned short)(r >> 16);
}
__device__ __forceinline__ unsigned pk2(float lo, float hi) {
  return (unsigned)f2bf(lo) | ((unsigned)f2bf(hi) << 16);
}
__device__ __forceinline__ f32x16 zero16() {
  f32x16 z;
#pragma unroll
  for (int i = 0; i < 16; ++i) z[i] = 0.f;
  return z;
}

// P -> MFMA-A fragment relayout for one 16-key slot (exchange across lane^32).
#define MK_PA(dst, hi_, a0,a1,a2,a3,a4,a5,a6,a7)                         \
  {                                                                      \
    unsigned x0 = pk2(a0, a1), x1 = pk2(a2, a3);                         \
    unsigned y0 = pk2(a4, a5), y1 = pk2(a6, a7);                         \
    unsigned t0 = (unsigned)__shfl_xor((int)((hi_) ? x0 : y0), 32);      \
    if (hi_) x0 = t0; else y0 = t0;                                      \
    unsigned t1 = (unsigned)__shfl_xor((int)((hi_) ? x1 : y1), 32);      \
    if (hi_) x1 = t1; else y1 = t1;                                      \
    U8 w_; w_.u[0] = x0; w_.u[1] = x1; w_.u[2] = y0; w_.u[3] = y1;       \
    dst = w_.s;                                                          \
  }

// ---------------------------------------------------------------------------
__global__ void k_setup(const int* __restrict__ mask,
                        int* __restrict__ gpos, int* __restrict__ gcount) {
  const int b = blockIdx.x;
  const int t = threadIdx.x;  // 64
  __shared__ int cnt[64];
  if (t < CG) gpos[b * CG + t] = 0;
  const int span = CS / 64;
  const int base = b * CS + t * span;
  int c = 0;
  for (int i = 0; i < span; ++i) c += (mask[base + i] > 0) ? 1 : 0;
  cnt[t] = c;
  __syncthreads();
  int pre = 0;
  for (int j = 0; j < t; ++j) pre += cnt[j];
  for (int i = 0; i < span; ++i) {
    if (mask[base + i] > 0) {
      if (pre < CG) gpos[b * CG + pre] = t * span + i;
      ++pre;
    }
  }
  if (t == 63) gcount[b] = (pre < CG) ? pre : CG;
}

// ---------------------------------------------------------------------------
// Fused main kernel (512 blocks, all co-resident).
// blockIdx.x < NS1 : part-1 -- stage gK/gV ONCE, loop 4 q-windows of 128.
// else             : part-2 -- q once; loop 4 key-windows of 128 with
//                    register-prefetch staging; ONE-SHOT softmax per window,
//                    flash partial per (window, key-half)  [r8 contract].
// ---------------------------------------------------------------------------
struct __align__(16) SMemP1 { short sK[64 * 64]; short sVT[64 * 64]; };
struct __align__(16) SMemP2 { short sK2[2][64 * 64]; short sVT2[2][64 * 64]; };
union __align__(16) SMem { SMemP1 p1; SMemP2 p2; };

__global__ __launch_bounds__(256, 2) void k_main(
    const float* __restrict__ q, const float* __restrict__ k,
    const float* __restrict__ v,
    const int* __restrict__ gpos, const int* __restrict__ gcount,
    float* __restrict__ ctx, float* __restrict__ probs,
    float* __restrict__ pm, float* __restrict__ pl,
    unsigned short* __restrict__ pctx) {
  __shared__ SMem sm;
  const int bh = blockIdx.y, b = bh / CH, t = threadIdx.x;
  const int lane = t & 63, wv = t >> 6;
  const int hi = lane >> 5, ql = lane & 31;
  const unsigned kswz = (unsigned)((ql & 7) << 4);
  const bool isP1 = (blockIdx.x < NS1);

  if (isP1) {
    // ============================ part 1 =================================
    const int bx1 = blockIdx.x;
    const int gc = gcount[b];
    // ---- stage gathered K / V^T once ----
    if (t < 128) {  // K rows
      const int row = t >> 1, c0 = (t & 1) * 32;
      const int grow = gpos[b * CG + row];
      const float* src = k + ((size_t)(bh * CS + grow)) * CD + c0;
      fvec4 ra[8];
#pragma unroll
      for (int i = 0; i < 4; ++i) {
        ra[2 * i]     = *(const fvec4*)(src + i * 8);
        ra[2 * i + 1] = *(const fvec4*)(src + i * 8 + 4);
      }
      const unsigned swz = (unsigned)((row & 7) << 4);
      char* rb = (char*)sm.p1.sK + row * 128;
#pragma unroll
      for (int i = 0; i < 4; ++i) {
        U8 w;
        w.u[0] = pk2(ra[2 * i][0], ra[2 * i][1]);
        w.u[1] = pk2(ra[2 * i][2], ra[2 * i][3]);
        w.u[2] = pk2(ra[2 * i + 1][0], ra[2 * i + 1][1]);
        w.u[3] = pk2(ra[2 * i + 1][2], ra[2 * i + 1][3]);
        *(short8*)(rb + (((unsigned)(c0 * 2 + i * 16)) ^ swz)) = w.s;
      }
    } else {  // V rows transposed
      const int u = t - 128;
      const int kg = u >> 4, cg = u & 15;
      int gi[8];
#pragma unroll
      for (int i = 0; i < 8; ++i) gi[i] = gpos[b * CG + 8 * kg + i];
      fvec4 rv[8];
#pragma unroll
      for (int i = 0; i < 8; ++i)
        rv[i] = *(const fvec4*)(v + ((size_t)(bh * CS + gi[i])) * CD + 4 * cg);
#pragma unroll
      for (int c = 0; c < 4; ++c) {
        const int row = 4 * cg + c;
        U8 w;
        w.u[0] = pk2(rv[0][c], rv[1][c]); w.u[1] = pk2(rv[2][c], rv[3][c]);
        w.u[2] = pk2(rv[4][c], rv[5][c]); w.u[3] = pk2(rv[6][c], rv[7][c]);
        *(short8*)((char*)sm.p1.sVT + row * 128 +
                   (((unsigned)(16 * kg)) ^ ((unsigned)((row & 7) << 4)))) = w.s;
      }
    }
    __syncthreads();

    // ---- loop 4 q-windows (barrier-free; loads pipeline across iters) ----
#pragma unroll
    for (int it = 0; it < 4; ++it) {
      const int qbase = (bx1 * 4 + it) * 128;
      const int qrow = qbase + wv * 32 + ql;
      const float* qr = q + ((size_t)(bh * CS + qrow)) * CD + hi * 8;
      fvec4 qa[8];
#pragma unroll
      for (int s = 0; s < 4; ++s) {
        qa[2 * s]     = *(const fvec4*)(qr + s * 16);
        qa[2 * s + 1] = *(const fvec4*)(qr + s * 16 + 4);
      }
      short8 qf[4];
#pragma unroll
      for (int s = 0; s < 4; ++s) {
        U8 w;
        w.u[0] = pk2(qa[2 * s][0] * 0.125f, qa[2 * s][1] * 0.125f);
        w.u[1] = pk2(qa[2 * s][2] * 0.125f, qa[2 * s][3] * 0.125f);
        w.u[2] = pk2(qa[2 * s + 1][0] * 0.125f, qa[2 * s + 1][1] * 0.125f);
        w.u[3] = pk2(qa[2 * s + 1][2] * 0.125f, qa[2 * s + 1][3] * 0.125f);
        qf[s] = w.s;
      }

      f32x16 acc0 = zero16(), acc1 = zero16();
#pragma unroll
      for (int s = 0; s < 4; ++s) {
        const unsigned off = ((unsigned)(32 * s + 16 * hi)) ^ kswz;
        short8 k0 = *(const short8*)((char*)sm.p1.sK + ql * 128 + off);
        acc0 = __builtin_amdgcn_mfma_f32_32x32x16_bf16(k0, qf[s], acc0, 0, 0, 0);
        short8 k1 = *(const short8*)((char*)sm.p1.sK + (32 + ql) * 128 + off);
        acc1 = __builtin_amdgcn_mfma_f32_32x32x16_bf16(k1, qf[s], acc1, 0, 0, 0);
      }

      float e0[16], e1[16];
      float m = -1e30f;
#pragma unroll
      for (int r = 0; r < 16; ++r) {
        const int key0 = (r & 3) + 8 * (r >> 2) + 4 * hi;
        float x0 = (key0 < gc) ? acc0[r] : -1e30f;
        float x1 = (key0 + 32 < gc) ? acc1[r] : -1e30f;
        e0[r] = x0; e1[r] = x1;
        m = fmaxf(m, fmaxf(x0, x1));
      }
      m = fmaxf(m, __shfl_xor(m, 32));
      float ls = 0.f;
#pragma unroll
      for (int r = 0; r < 16; ++r) {
        e0[r] = __expf(e0[r] - m); ls += e0[r];
        e1[r] = __expf(e1[r] - m); ls += e1[r];
      }
      ls += __shfl_xor(ls, 32);
      const float inv = 1.0f / ls;
#pragma unroll
      for (int r = 0; r < 16; ++r) { e0[r] *= inv; e1[r] *= inv; }

      float* prow = probs + ((size_t)(bh * CS + qrow)) * CG;
#pragma unroll
      for (int g4 = 0; g4 < 4; ++g4) {
        fvec4 o0 = {e0[4 * g4], e0[4 * g4 + 1], e0[4 * g4 + 2], e0[4 * g4 + 3]};
        fvec4 o1 = {e1[4 * g4], e1[4 * g4 + 1], e1[4 * g4 + 2], e1[4 * g4 + 3]};
        *(fvec4*)(prow + 8 * g4 + 4 * hi) = o0;
        *(fvec4*)(prow + 8 * g4 + 4 * hi + 32) = o1;
      }

      short8 pa0, pa1, pa2, pa3;
      MK_PA(pa0, hi, e0[0], e0[1], e0[2], e0[3], e0[4], e0[5], e0[6], e0[7]);
      MK_PA(pa1, hi, e0[8], e0[9], e0[10], e0[11], e0[12], e0[13], e0[14], e0[15]);
      MK_PA(pa2, hi, e1[0], e1[1], e1[2], e1[3], e1[4], e1[5], e1[6], e1[7]);
      MK_PA(pa3, hi, e1[8], e1[9], e1[10], e1[11], e1[12], e1[13], e1[14], e1[15]);

      f32x16 oc0 = zero16(), oc1 = zero16();
#pragma unroll
      for (int s = 0; s < 4; ++s) {
        const short8 pas = (s == 0) ? pa0 : (s == 1) ? pa1 : (s == 2) ? pa2 : pa3;
        const unsigned off = ((unsigned)(32 * s + 16 * hi)) ^ kswz;
        short8 v0 = *(const short8*)((char*)sm.p1.sVT + ql * 128 + off);
        oc0 = __builtin_amdgcn_mfma_f32_32x32x16_bf16(pas, v0, oc0, 0, 0, 0);
        short8 v1 = *(const short8*)((char*)sm.p1.sVT + (32 + ql) * 128 + off);
        oc1 = __builtin_amdgcn_mfma_f32_32x32x16_bf16(pas, v1, oc1, 0, 0, 0);
      }

      float* cb = ctx + ((size_t)(bh * CS + qbase + wv * 32)) * CD;
#pragma unroll
      for (int r = 0; r < 16; ++r) {
        const int qr2 = (r & 3) + 8 * (r >> 2) + 4 * hi;
        cb[(size_t)qr2 * CD + ql] = oc0[r];
        cb[(size_t)qr2 * CD + 32 + ql] = oc1[r];
      }
    }
  } else {
    // ============================ part 2 =================================
    const int bx2 = blockIdx.x - NS1;
    const int qt = wv & 1, kh = wv >> 1;
    const int qslot = qt * 32 + ql;

    // q fragments once
    const int gq = gpos[b * CG + qslot];
    const float* qr = q + ((size_t)(bh * CS + gq)) * CD + hi * 8;
    fvec4 qa[8];
#pragma unroll
    for (int s = 0; s < 4; ++s) {
      qa[2 * s]     = *(const fvec4*)(qr + s * 16);
      qa[2 * s + 1] = *(const fvec4*)(qr + s * 16 + 4);
    }
    short8 qf[4];
#pragma unroll
    for (int s = 0; s < 4; ++s) {
      U8 w;
      w.u[0] = pk2(qa[2 * s][0] * 0.125f, qa[2 * s][1] * 0.125f);
      w.u[1] = pk2(qa[2 * s][2] * 0.125f, qa[2 * s][3] * 0.125f);
      w.u[2] = pk2(qa[2 * s + 1][0] * 0.125f, qa[2 * s + 1][1] * 0.125f);
      w.u[3] = pk2(qa[2 * s + 1][2] * 0.125f, qa[2 * s + 1][3] * 0.125f);
      qf[s] = w.s;
    }

    // staging-role constants
    const int krow = t >> 1, kc0 = (t & 1) * 32;          // t<128 (K)
    const int vu = t - 128, vkg = vu >> 4, vcg = vu & 15; // t>=128 (V)

    // prologue: issue window-0 loads into regs
    fvec4 scur[16], snxt[16];
    {
      const int kwin = (bx2 * 4) * 128;
      if (t < 128) {
#pragma unroll
        for (int h = 0; h < 2; ++h) {
          const float* src =
              k + ((size_t)(bh * CS + kwin + h * 64 + krow)) * CD + kc0;
#pragma unroll
          for (int i = 0; i < 4; ++i) {
            scur[h * 8 + 2 * i]     = *(const fvec4*)(src + i * 8);
            scur[h * 8 + 2 * i + 1] = *(const fvec4*)(src + i * 8 + 4);
          }
        }
      } else {
#pragma unroll
        for (int h = 0; h < 2; ++h)
#pragma unroll
          for (int i = 0; i < 8; ++i)
            scur[h * 8 + i] = *(const fvec4*)(
                v + ((size_t)(bh * CS + kwin + h * 64 + 8 * vkg + i)) * CD +
                4 * vcg);
      }
    }

#pragma unroll
    for (int u = 0; u < 4; ++u) {
      // ---- convert + ds_write current window ----
      if (t < 128) {
        const unsigned swz = (unsigned)((krow & 7) << 4);
#pragma unroll
        for (int h = 0; h < 2; ++h) {
          char* rb = (char*)sm.p2.sK2[h] + krow * 128;
#pragma unroll
          for (int i = 0; i < 4; ++i) {
            U8 w;
            w.u[0] = pk2(scur[h * 8 + 2 * i][0], scur[h * 8 + 2 * i][1]);
            w.u[1] = pk2(scur[h * 8 + 2 * i][2], scur[h * 8 + 2 * i][3]);
            w.u[2] = pk2(scur[h * 8 + 2 * i + 1][0], scur[h * 8 + 2 * i + 1][1]);
            w.u[3] = pk2(scur[h * 8 + 2 * i + 1][2], scur[h * 8 + 2 * i + 1][3]);
            *(short8*)(rb + (((unsigned)(kc0 * 2 + i * 16)) ^ swz)) = w.s;
          }
        }
      } else {
#pragma unroll
        for (int h = 0; h < 2; ++h)
#pragma unroll
          for (int c = 0; c < 4; ++c) {
            const int row = 4 * vcg + c;
            U8 w;
            w.u[0] = pk2(scur[h * 8 + 0][c], scur[h * 8 + 1][c]);
            w.u[1] = pk2(scur[h * 8 + 2][c], scur[h * 8 + 3][c]);
            w.u[2] = pk2(scur[h * 8 + 4][c], scur[h * 8 + 5][c]);
            w.u[3] = pk2(scur[h * 8 + 6][c], scur[h * 8 + 7][c]);
            *(short8*)((char*)sm.p2.sVT2[h] + row * 128 +
                       (((unsigned)(16 * vkg)) ^
                        ((unsigned)((row & 7) << 4)))) = w.s;
          }
      }
      __syncthreads();

      // ---- issue next window's loads (overlap with compute) ----
      if (u < 3) {
        const int kwin = (bx2 * 4 + u + 1) * 128;
        if (t < 128) {
#pragma unroll
          for (int h = 0; h < 2; ++h) {
            const float* src =
                k + ((size_t)(bh * CS + kwin + h * 64 + krow)) * CD + kc0;
#pragma unroll
            for (int i = 0; i < 4; ++i) {
              snxt[h * 8 + 2 * i]     = *(const fvec4*)(src + i * 8);
              snxt[h * 8 + 2 * i + 1] = *(const fvec4*)(src + i * 8 + 4);
            }
          }
        } else {
#pragma unroll
          for (int h = 0; h < 2; ++h)
#pragma unroll
            for (int i = 0; i < 8; ++i)
              snxt[h * 8 + i] = *(const fvec4*)(
                  v + ((size_t)(bh * CS + kwin + h * 64 + 8 * vkg + i)) * CD +
                  4 * vcg);
        }
      }

      // ---- compute window u (wave's 64-key half), ONE-SHOT softmax ----
      const char* bK = (const char*)sm.p2.sK2[kh];
      const char* bVT = (const char*)sm.p2.sVT2[kh];

      f32x16 acc0 = zero16(), acc1 = zero16();
#pragma unroll
      for (int s = 0; s < 4; ++s) {
        const unsigned off = ((unsigned)(32 * s + 16 * hi)) ^ kswz;
        short8 k0 = *(const short8*)(bK + ql * 128 + off);
        acc0 = __builtin_amdgcn_mfma_f32_32x32x16_bf16(k0, qf[s], acc0, 0, 0, 0);
        short8 k1 = *(const short8*)(bK + (32 + ql) * 128 + off);
        acc1 = __builtin_amdgcn_mfma_f32_32x32x16_bf16(k1, qf[s], acc1, 0, 0, 0);
      }

      float e0[16], e1[16];
      float m = -1e30f;
#pragma unroll
      for (int r = 0; r < 16; ++r) {
        e0[r] = acc0[r]; e1[r] = acc1[r];
        m = fmaxf(m, fmaxf(e0[r], e1[r]));
      }
      m = fmaxf(m, __shfl_xor(m, 32));
      float ls = 0.f;
#pragma unroll
      for (int r = 0; r < 16; ++r) {
        e0[r] = __expf(e0[r] - m); ls += e0[r];
        e1[r] = __expf(e1[r] - m); ls += e1[r];
      }
      ls += __shfl_xor(ls, 32);

      short8 pa0, pa1, pa2, pa3;
      MK_PA(pa0, hi, e0[0], e0[1], e0[2], e0[3], e0[4], e0[5], e0[6], e0[7]);
      MK_PA(pa1, hi, e0[8], e0[9], e0[10], e0[11], e0[12], e0[13], e0[14], e0[15]);
      MK_PA(pa2, hi, e1[0], e1[1], e1[2], e1[3], e1[4], e1[5], e1[6], e1[7]);
      MK_PA(pa3, hi, e1[8], e1[9], e1[10], e1[11], e1[12], e1[13], e1[14], e1[15]);

      f32x16 oc0 = zero16(), oc1 = zero16();
#pragma unroll
      for (int s = 0; s < 4; ++s) {
        const short8 pas = (s == 0) ? pa0 : (s == 1) ? pa1 : (s == 2) ? pa2 : pa3;
        const unsigned off = ((unsigned)(32 * s + 16 * hi)) ^ kswz;
        short8 v0 = *(const short8*)(bVT + ql * 128 + off);
        oc0 = __builtin_amdgcn_mfma_f32_32x32x16_bf16(pas, v0, oc0, 0, 0, 0);
        short8 v1 = *(const short8*)(bVT + (32 + ql) * 128 + off);
        oc1 = __builtin_amdgcn_mfma_f32_32x32x16_bf16(pas, v1, oc1, 0, 0, 0);
      }
      __syncthreads();  // LDS consumed before next iteration's ds_write

      // ---- flash partial for this window (r8 contract) ----
      const int part = (bx2 * 4 + u) * 2 + kh;
      if (hi == 0) {
        const size_t o = ((size_t)(bh * NPART + part)) * CG + qslot;
        pm[o] = m;
        pl[o] = ls;
      }
      unsigned short* po =
          pctx + (((size_t)(bh * NPART + part)) * CG + qt * 32) * CD;
#pragma unroll
      for (int r = 0; r < 16; ++r) {
        const int qr2 = (r & 3) + 8 * (r >> 2) + 4 * hi;
        po[(size_t)qr2 * CD + ql] = f2bf(oc0[r]);
        po[(size_t)qr2 * CD + 32 + ql] = f2bf(oc1[r]);
      }

      if (u < 3) {
#pragma unroll
        for (int i = 0; i < 16; ++i) scur[i] = snxt[i];
      }
    }
  }
}

// ---------------------------------------------------------------------------
// Combine: 256 threads = 4 c-groups x 64 d; 16-deep chains + LDS reduction.
// ---------------------------------------------------------------------------
__global__ __launch_bounds__(256) void k_combine(
    const float* __restrict__ pm, const float* __restrict__ pl,
    const unsigned short* __restrict__ pctx,
    const int* __restrict__ gpos, const int* __restrict__ gcount,
    float* __restrict__ ctx) {
  const int g = blockIdx.x;
  const int bh = blockIdx.y;
  const int b = bh / CH;
  if (g >= gcount[b]) return;
  const int t = threadIdx.x;
  const int cg = t >> 6, d = t & 63;
  __shared__ float smax[4];
  __shared__ float sl[4];
  __shared__ float sacc[4][64];

  float lm = -1e30f;
#pragma unroll
  for (int j = 0; j < 16; ++j) {
    const int c = cg * 16 + j;
    lm = fmaxf(lm, pm[((size_t)(bh * NPART + c)) * CG + g]);
  }
  if (d == 0) smax[cg] = lm;
  __syncthreads();
  const float m = fmaxf(fmaxf(smax[0], smax[1]), fmaxf(smax[2], smax[3]));

  float L = 0.f, acc = 0.f;
#pragma unroll
  for (int j = 0; j < 16; ++j) {
    const int c = cg * 16 + j;
    const size_t o = ((size_t)(bh * NPART + c)) * CG + g;
    const float w = __expf(pm[o] - m);
    L = fmaf(w, pl[o], L);
    const float x = __uint_as_float((unsigned)pctx[o * CD + d] << 16);
    acc = fmaf(w, x, acc);
  }
  sacc[cg][d] = acc;
  if (d == 0) sl[cg] = L;
  __syncthreads();
  if (cg == 0) {
    const float A = sacc[0][d] + sacc[1][d] + sacc[2][d] + sacc[3][d];
    const float Lt = sl[0] + sl[1] + sl[2] + sl[3];
    const int tok = gpos[b * CG + g];
    ctx[((size_t)(bh * CS + tok)) * CD + d] = A / Lt;
  }
}

extern "C" void kernel_launch(void* const* d_in, const int* in_sizes, int n_in,
                              void* d_out, int out_size, void* d_ws, size_t ws_size,
                              hipStream_t stream) {
  const float* q = (const float*)d_in[0];
  const float* k = (const float*)d_in[1];
  const float* v = (const float*)d_in[2];
  const int* mask = (const int*)d_in[3];

  float* ctx = (float*)d_out;
  float* probs = ctx + (size_t)CBH * CS * CD;

  char* ws = (char*)d_ws;
  int* gpos = (int*)ws;                                  // 512 B
  int* gcount = (int*)(ws + 512);                        // 512 B
  float* pm = (float*)(ws + 1024);                       // CBH*NPART*CG f32
  float* pl = pm + (size_t)CBH * NPART * CG;             // CBH*NPART*CG f32
  unsigned short* pctx =
      (unsigned short*)(pl + (size_t)CBH * NPART * CG);  // CBH*NPART*CG*CD bf16

  k_setup<<<dim3(CB), dim3(64), 0, stream>>>(mask, gpos, gcount);
  k_main<<<dim3(NS1 + NS2, CBH), dim3(256), 0, stream>>>(
      q, k, v, gpos, gcount, ctx, probs, pm, pl, pctx);
  k_combine<<<dim3(CG, CBH), dim3(256), 0, stream>>>(
      pm, pl, pctx, gpos, gcount, ctx);
}